// Round 7
// baseline (250.058 us; speedup 1.0000x reference)
//
#include <hip/hip_runtime.h>
#include <math.h>

#define N_ENT  50000
#define N_REL  200
#define N_EDGE 1000000
#define CHUNK  196    // ceil(N_ENT/256) for scans
#define NCH    64     // edge chunks
#define ECH2   15625  // N_EDGE/NCH (exact)
#define NPART  8      // node-range partitions
#define NRNG   6250   // N_ENT/NPART (exact)

// ---- ws byte offsets (peak ~25.3MB) ----
#define WS_MISC   0          // int is64
#define WS_ZSUM   128        // double
#define WS_ZMID   192        // float
#define WS_AV     256        // float[64]
#define WS_BV     512        // float[64]
#define WS_BSUM   0x00010000 // int[256]
#define WS_BBASE  0x00011000 // int[256]
#define WS_TOT    0x00040000 // int[N_ENT]
#define WS_OFFS   0x00080000 // int[N_ENT+1]
#define WS_ZSRC   0x000C0000 // float[N_ENT]
#define WS_ZDST   0x00100000 // float[N_ENT]
#define WS_SNODE  0x00140000 // float[N_ENT]
#define WS_SRCS   0x00180000 // ushort[N_EDGE]          (2MB, dead after scatter)
#define WS_EB     0x00380000 // uint[N_EDGE] packed     (4MB, dead after scatter)
#define WS_EPK    0x00780000 // uint[N_EDGE] CSR packed (4MB, live)
#define WS_HIST   0x00B80000 // ushort[NCH][N_ENT]      (6.4MB, dead after scatter)
#define WS_XB1    0x00B80000 // ushort[N_ENT*64] — aliases HIST (first write after scatter)
#define WS_XB0    0x01200000 // ushort[N_ENT*64]

__device__ __forceinline__ float bflo(unsigned u) { return __uint_as_float(u << 16); }
__device__ __forceinline__ float bfhi(unsigned u) { return __uint_as_float(u & 0xffff0000u); }
__device__ __forceinline__ unsigned short f2bf(float f) {  // RNE
  unsigned u = __float_as_uint(f);
  unsigned r = ((u >> 16) & 1u) + 0x7fffu;
  return (unsigned short)((u + r) >> 16);
}
__device__ __forceinline__ float lanebc(float v, int k) {
  return __uint_as_float((unsigned)__builtin_amdgcn_readlane((int)__float_as_uint(v), k));
}
__device__ __forceinline__ float fast_tanh(float x) {
  float ex = __expf(2.f * x);
  return 1.f - __fdividef(2.f, ex + 1.f);
}
__device__ __forceinline__ void fma8(float* acc, float wt, uint4 q) {
  acc[0] += wt * bflo(q.x); acc[1] += wt * bfhi(q.x);
  acc[2] += wt * bflo(q.y); acc[3] += wt * bfhi(q.y);
  acc[4] += wt * bflo(q.z); acc[5] += wt * bfhi(q.z);
  acc[6] += wt * bflo(q.w); acc[7] += wt * bfhi(q.w);
}

__global__ void k_init(const void* tri, int* misc, double* zsum) {
  if (blockIdx.x == 0 && threadIdx.x < 64) {
    int l = threadIdx.x;
    int z = ((const int*)tri)[2 * l + 1];
    unsigned long long m = __ballot(z == 0);
    if (l == 0) { misc[0] = (m == ~0ull) ? 1 : 0; *zsum = 0.0; }
  }
}

__global__ void k_conv(const float* __restrict__ x, unsigned short* __restrict__ xb) {
  int i = blockIdx.x * blockDim.x + threadIdx.x;   // 800K quads
  if (i >= N_ENT * 16) return;
  float4 v = ((const float4*)x)[i];
  ushort4 o;
  o.x = f2bf(v.x); o.y = f2bf(v.y); o.z = f2bf(v.z); o.w = f2bf(v.w);
  ((ushort4*)xb)[i] = o;
}

// pure streaming decode: no atomics
__global__ void k_decode(const void* tri, unsigned short* __restrict__ srcs,
                         unsigned* __restrict__ eb, const int* misc) {
  int is64 = misc[0];
  int stride = gridDim.x * blockDim.x;
  if (is64) {
    const long long* t = (const long long*)tri;
    for (int e = blockIdx.x * blockDim.x + threadIdx.x; e < N_EDGE; e += stride) {
      int s = (int)t[3 * e], r = (int)t[3 * e + 1], d = (int)t[3 * e + 2];
      srcs[e] = (unsigned short)s;
      eb[e] = ((unsigned)r << 16) | (unsigned)d;
    }
  } else {
    const int* t = (const int*)tri;
    for (int e = blockIdx.x * blockDim.x + threadIdx.x; e < N_EDGE; e += stride) {
      int s = t[3 * e], r = t[3 * e + 1], d = t[3 * e + 2];
      srcs[e] = (unsigned short)s;
      eb[e] = ((unsigned)r << 16) | (unsigned)d;
    }
  }
}

// per-(chunk, node-range) histogram in LDS; no global atomics
__global__ void __launch_bounds__(256) k_hist(const unsigned short* __restrict__ srcs,
                                              unsigned short* __restrict__ hist) {
  __shared__ unsigned h[NRNG];
  int c = blockIdx.x >> 3, x = blockIdx.x & 7;
  int lo = x * NRNG;
  for (int i = threadIdx.x; i < NRNG; i += 256) h[i] = 0u;
  __syncthreads();
  int e0 = c * ECH2, e1 = e0 + ECH2;
  for (int e = e0 + threadIdx.x; e < e1; e += 256) {
    int rel = (int)srcs[e] - lo;
    if ((unsigned)rel < NRNG) atomicAdd(&h[rel], 1u);
  }
  __syncthreads();
  for (int i = threadIdx.x; i < NRNG; i += 256)
    hist[c * N_ENT + lo + i] = (unsigned short)h[i];
}

// in-place exclusive scan over chunks per node: hist -> cbase; tot[s] = total
__global__ void k_scanH(unsigned short* __restrict__ hist, int* __restrict__ tot) {
  int s = blockIdx.x * blockDim.x + threadIdx.x;
  if (s >= N_ENT) return;
  int run = 0;
  for (int c = 0; c < NCH; c++) {
    int v = hist[c * N_ENT + s];
    hist[c * N_ENT + s] = (unsigned short)run;
    run += v;
  }
  tot[s] = run;
}

__global__ void k_scanA(const int* __restrict__ counts, int* __restrict__ bsum) {
  __shared__ int sm[4];
  int t = threadIdx.x;
  int i = blockIdx.x * CHUNK + t;
  int v = (t < CHUNK && i < N_ENT) ? counts[i] : 0;
  for (int o = 32; o; o >>= 1) v += __shfl_down(v, o);
  if ((t & 63) == 0) sm[t >> 6] = v;
  __syncthreads();
  if (t == 0) bsum[blockIdx.x] = sm[0] + sm[1] + sm[2] + sm[3];
}

__global__ void k_scanB(const int* __restrict__ bsum, int* __restrict__ bbase, int* __restrict__ offs) {
  __shared__ int sm[256];
  int t = threadIdx.x;
  int v = bsum[t];
  sm[t] = v;
  __syncthreads();
  for (int d = 1; d < 256; d <<= 1) {
    int x = (t >= d) ? sm[t - d] : 0;
    __syncthreads();
    sm[t] += x;
    __syncthreads();
  }
  bbase[t] = sm[t] - v;
  if (t == 255) offs[N_ENT] = sm[255];
}

__global__ void k_scanC(const int* __restrict__ counts, const int* __restrict__ bbase,
                        int* __restrict__ offs) {
  __shared__ int sm[256];
  int t = threadIdx.x;
  int i = blockIdx.x * CHUNK + t;
  int v = (t < CHUNK && i < N_ENT) ? counts[i] : 0;
  sm[t] = v;
  __syncthreads();
  for (int d = 1; d < 256; d <<= 1) {
    int x = (t >= d) ? sm[t - d] : 0;
    __syncthreads();
    sm[t] += x;
    __syncthreads();
  }
  if (t < CHUNK && i < N_ENT)
    offs[i] = bbase[blockIdx.x] + sm[t] - v;
}

// scatter with LDS-computed local ranks; slot = offs[s] + cbase[c][s] + lrank
__global__ void __launch_bounds__(256) k_scatter(
    const unsigned short* __restrict__ srcs, const unsigned* __restrict__ eb,
    const unsigned short* __restrict__ cbase, const int* __restrict__ offs,
    unsigned* __restrict__ epk) {
  __shared__ unsigned h[NRNG];
  int c = blockIdx.x >> 3, x = blockIdx.x & 7;
  int lo = x * NRNG;
  for (int i = threadIdx.x; i < NRNG; i += 256) h[i] = 0u;
  __syncthreads();
  int e0 = c * ECH2, e1 = e0 + ECH2;
  for (int e = e0 + threadIdx.x; e < e1; e += 256) {
    int s = (int)srcs[e];
    int rel = s - lo;
    if ((unsigned)rel < NRNG) {
      int lr = atomicAdd(&h[rel], 1u);
      epk[offs[s] + (int)cbase[c * N_ENT + s] + lr] = eb[e];
    }
  }
}

__global__ void k_pre(const float* u, const float* enw, const float* rew, const float* rsp,
                      float* a, float* b, float* zmid) {
  int k = threadIdx.x;  // 64
  float aa = 0.f, bb = 0.f;
  for (int j = 0; j < 64; j++) {
    float w = enw[j * 64 + k];
    aa += u[j] * w;
    bb += u[128 + j] * w;
  }
  a[k] = aa; b[k] = bb;
  float t = 0.f;
  for (int c = 0; c < 64; c++) t += rew[k * 64 + c] * rsp[c];
  t *= u[64 + k];
  for (int o = 32; o; o >>= 1) t += __shfl_down(t, o);
  if (k == 0) *zmid = t;
}

// one wave per node; 8 lanes per edge, 16B per lane; dummies read row 0 (L1-hot)
template <int EPI>
__global__ void __launch_bounds__(256) k_wgc(
    const unsigned short* __restrict__ xb, const float* __restrict__ W,
    const int* __restrict__ offs, const unsigned* __restrict__ epk,
    const float* __restrict__ re_att, unsigned short* __restrict__ yb,
    const float* __restrict__ a, const float* __restrict__ b,
    float* __restrict__ zsrc, float* __restrict__ zdst) {
  __shared__ float s_att[N_REL];
  for (int t = threadIdx.x; t < N_REL; t += 256) s_att[t] = re_att[t];
  __syncthreads();
  int wid = (blockIdx.x * blockDim.x + threadIdx.x) >> 6;
  int lane = threadIdx.x & 63;
  if (wid >= N_ENT) return;
  int node = wid;
  int g = lane >> 3, c8 = (lane & 7) * 8;
  int e0 = offs[node], e1 = offs[node + 1];
  float acc[8] = {0.f, 0.f, 0.f, 0.f, 0.f, 0.f, 0.f, 0.f};
  {
    uint4 q = *(const uint4*)(xb + (size_t)node * 64 + c8);
    fma8(acc, (g == 0) ? 1.f : 0.f, q);
  }
  for (int e = e0; e < e1; e += 16) {
    int ia = e + g, ib = ia + 8;
    bool va = ia < e1, vb = ib < e1;
    unsigned pa = epk[va ? ia : e0];
    unsigned pb = epk[vb ? ib : e0];
    float wa = va ? s_att[pa >> 16] : 0.f;
    float wb = vb ? s_att[pb >> 16] : 0.f;
    unsigned ra = va ? (pa & 0xffffu) : 0u;
    unsigned rb = vb ? (pb & 0xffffu) : 0u;
    uint4 qa = *(const uint4*)(xb + (size_t)ra * 64 + c8);
    uint4 qb = *(const uint4*)(xb + (size_t)rb * 64 + c8);
    fma8(acc, wa, qa);
    fma8(acc, wb, qb);
  }
#pragma unroll
  for (int off = 8; off <= 32; off <<= 1)
#pragma unroll
    for (int c = 0; c < 8; c++) acc[c] += __shfl_xor(acc[c], off);
  float o = 0.f;
#pragma unroll
  for (int j = 0; j < 8; j++)
#pragma unroll
    for (int c = 0; c < 8; c++)
      o += lanebc(acc[c], j) * W[(j * 8 + c) * 64 + lane];
  float yv = fast_tanh(o);
  yb[(size_t)node * 64 + lane] = f2bf(yv);
  if (EPI) {
    float za = yv * a[lane], zb = yv * b[lane];
    for (int s = 32; s; s >>= 1) { za += __shfl_down(za, s); zb += __shfl_down(zb, s); }
    if (lane == 0) { zsrc[node] = za; zdst[node] = zb; }
  }
}

// unnormalized attention aggregate + per-node partial softmax sums
__global__ void __launch_bounds__(256) k_out(
    const unsigned short* __restrict__ xb, const int* __restrict__ offs,
    const unsigned* __restrict__ epk, const float* __restrict__ zs,
    const float* __restrict__ zd, const float* zmid,
    float* __restrict__ out, float* __restrict__ snode) {
  int wid = (blockIdx.x * blockDim.x + threadIdx.x) >> 6;
  int lane = threadIdx.x & 63;
  if (wid >= N_ENT) return;
  int node = wid;
  int g = lane >> 3, c8 = (lane & 7) * 8;
  float zi = zs[node] + *zmid;
  float acc[8] = {0.f, 0.f, 0.f, 0.f, 0.f, 0.f, 0.f, 0.f};
  float s0 = 0.f;
  int e0 = offs[node], e1 = offs[node + 1];
  for (int e = e0; e < e1; e += 16) {
    int ia = e + g, ib = ia + 8;
    bool va = ia < e1, vb = ib < e1;
    unsigned pa = epk[va ? ia : e0];
    unsigned pb = epk[vb ? ib : e0];
    unsigned da = va ? (pa & 0xffffu) : 0u;
    unsigned db = vb ? (pb & 0xffffu) : 0u;
    float ca = zi + zd[da];
    float cb = zi + zd[db];
    ca = ca >= 0.f ? ca : 0.01f * ca;
    cb = cb >= 0.f ? cb : 0.01f * cb;
    float wa = va ? __expf(ca) : 0.f;
    float wb = vb ? __expf(cb) : 0.f;
    uint4 qa = *(const uint4*)(xb + (size_t)da * 64 + c8);
    uint4 qb = *(const uint4*)(xb + (size_t)db * 64 + c8);
    fma8(acc, wa, qa);
    fma8(acc, wb, qb);
    s0 += wa + wb;
  }
#pragma unroll
  for (int off = 8; off <= 32; off <<= 1) {
#pragma unroll
    for (int c = 0; c < 8; c++) acc[c] += __shfl_xor(acc[c], off);
    s0 += __shfl_xor(s0, off);
  }
  if (lane < 8) {
    float4* p = (float4*)(out + (size_t)node * 64 + lane * 8);
    p[0] = make_float4(acc[0], acc[1], acc[2], acc[3]);
    p[1] = make_float4(acc[4], acc[5], acc[6], acc[7]);
  }
  if (lane == 0) snode[node] = s0;
}

__global__ void k_red(const float* __restrict__ snode, double* zsum) {
  int stride = gridDim.x * blockDim.x;
  double s = 0.0;
  for (int i = blockIdx.x * blockDim.x + threadIdx.x; i < N_ENT; i += stride)
    s += (double)snode[i];
  for (int o = 32; o; o >>= 1) s += __shfl_down(s, o);
  __shared__ double ws_[4];
  if ((threadIdx.x & 63) == 0) ws_[threadIdx.x >> 6] = s;
  __syncthreads();
  if (threadIdx.x == 0)
    atomicAdd(zsum, ws_[0] + ws_[1] + ws_[2] + ws_[3]);
}

__global__ void k_norm(float* __restrict__ out, const double* zsum) {
  int i = blockIdx.x * blockDim.x + threadIdx.x;  // 800K quads
  if (i >= N_ENT * 16) return;
  float invZ = (float)(1.0 / *zsum);
  float4 v = ((float4*)out)[i];
  v.x *= invZ; v.y *= invZ; v.z *= invZ; v.w *= invZ;
  ((float4*)out)[i] = v;
}

extern "C" void kernel_launch(void* const* d_in, const int* in_sizes, int n_in,
                              void* d_out, int out_size, void* d_ws, size_t ws_size,
                              hipStream_t stream) {
  const float* emb   = (const float*)d_in[0];
  const float* reatt = (const float*)d_in[1];
  const float* W1    = (const float*)d_in[2];
  const float* W2    = (const float*)d_in[3];
  const float* W3    = (const float*)d_in[4];
  const float* u     = (const float*)d_in[5];
  const float* enw   = (const float*)d_in[6];
  const float* rew   = (const float*)d_in[7];
  const float* rsp   = (const float*)d_in[8];
  const void*  tri   = d_in[9];

  char* ws = (char*)d_ws;
  int*            misc   = (int*)(ws + WS_MISC);
  double*         zsum   = (double*)(ws + WS_ZSUM);
  float*          zmid   = (float*)(ws + WS_ZMID);
  float*          av     = (float*)(ws + WS_AV);
  float*          bv     = (float*)(ws + WS_BV);
  int*            bsum   = (int*)(ws + WS_BSUM);
  int*            bbase  = (int*)(ws + WS_BBASE);
  int*            tot    = (int*)(ws + WS_TOT);
  int*            offs   = (int*)(ws + WS_OFFS);
  float*          zsrc   = (float*)(ws + WS_ZSRC);
  float*          zdst   = (float*)(ws + WS_ZDST);
  float*          snode  = (float*)(ws + WS_SNODE);
  unsigned short* srcs   = (unsigned short*)(ws + WS_SRCS);
  unsigned*       eb     = (unsigned*)(ws + WS_EB);
  unsigned*       epk    = (unsigned*)(ws + WS_EPK);
  unsigned short* hist   = (unsigned short*)(ws + WS_HIST);
  unsigned short* xb0    = (unsigned short*)(ws + WS_XB0);
  unsigned short* xb1    = (unsigned short*)(ws + WS_XB1);  // aliases hist
  float*          out    = (float*)d_out;

  k_init<<<1, 64, 0, stream>>>(tri, misc, zsum);
  k_conv<<<3125, 256, 0, stream>>>(emb, xb0);
  k_decode<<<4096, 256, 0, stream>>>(tri, srcs, eb, misc);
  k_hist<<<NCH * NPART, 256, 0, stream>>>(srcs, hist);
  k_scanH<<<196, 256, 0, stream>>>(hist, tot);
  k_scanA<<<256, 256, 0, stream>>>(tot, bsum);
  k_scanB<<<1, 256, 0, stream>>>(bsum, bbase, offs);
  k_scanC<<<256, 256, 0, stream>>>(tot, bbase, offs);
  k_scatter<<<NCH * NPART, 256, 0, stream>>>(srcs, eb, hist, offs, epk);
  k_pre<<<1, 64, 0, stream>>>(u, enw, rew, rsp, av, bv, zmid);

  int nb = (N_ENT * 64 + 255) / 256;  // 12500 blocks, 4 node-waves each
  k_wgc<0><<<nb, 256, 0, stream>>>(xb0, W1, offs, epk, reatt, xb1, nullptr, nullptr, nullptr, nullptr);
  k_wgc<0><<<nb, 256, 0, stream>>>(xb1, W2, offs, epk, reatt, xb0, nullptr, nullptr, nullptr, nullptr);
  k_wgc<1><<<nb, 256, 0, stream>>>(xb0, W3, offs, epk, reatt, xb1, av, bv, zsrc, zdst);

  k_out<<<nb, 256, 0, stream>>>(xb1, offs, epk, zsrc, zdst, zmid, out, snode);
  k_red<<<196, 256, 0, stream>>>(snode, zsum);
  k_norm<<<3125, 256, 0, stream>>>(out, zsum);
}

// Round 9
// 224.101 us; speedup vs baseline: 1.1158x; 1.1158x over previous
//
#include <hip/hip_runtime.h>
#include <math.h>

#define N_ENT  50000
#define N_REL  200
#define N_EDGE 1000000
#define CHUNK  196    // ceil(N_ENT/256) for scans
#define NCH    64     // edge chunks
#define ECH2   15625  // N_EDGE/NCH (exact)
#define NPART  4      // node-range partitions
#define NRNG   12500  // N_ENT/NPART (exact)

// ---- ws byte offsets (peak ~25.3MB) ----
#define WS_ZSUM   128        // double
#define WS_ZMID   192        // float
#define WS_AV     256        // float[64]
#define WS_BV     512        // float[64]
#define WS_WT     0x00001000 // ushort[3][64*72] bf16 W^T padded (27.6KB)
#define WS_BSUM   0x00010000 // int[256]
#define WS_BBASE  0x00011000 // int[256]
#define WS_TOT    0x00040000 // int[N_ENT]
#define WS_OFFS   0x00080000 // int[N_ENT+1]
#define WS_ZSRC   0x000C0000 // float[N_ENT]
#define WS_ZDST   0x00100000 // float[N_ENT]
#define WS_SNODE  0x00140000 // float[N_ENT]
#define WS_SRCS   0x00180000 // ushort[N_EDGE]          (2MB, dead after scatter)
#define WS_EB     0x00380000 // uint[N_EDGE] packed     (4MB, dead after scatter)
#define WS_EPK    0x00780000 // uint[N_EDGE] CSR packed (4MB, live)
#define WS_HIST   0x00B80000 // ushort[NCH][N_ENT]      (6.4MB, dead after scatter)
#define WS_XB1    0x00B80000 // ushort[N_ENT*64] — aliases HIST (first write after scatter)
#define WS_XB0    0x01200000 // ushort[N_ENT*64]

typedef __attribute__((ext_vector_type(8))) short s16x8;
typedef __attribute__((ext_vector_type(4))) float f32x4;

__device__ __forceinline__ float bflo(unsigned u) { return __uint_as_float(u << 16); }
__device__ __forceinline__ float bfhi(unsigned u) { return __uint_as_float(u & 0xffff0000u); }
__device__ __forceinline__ float bf2f(unsigned short u) {
  return __uint_as_float(((unsigned)u) << 16);
}
__device__ __forceinline__ unsigned short f2bf(float f) {  // RNE
  unsigned u = __float_as_uint(f);
  unsigned r = ((u >> 16) & 1u) + 0x7fffu;
  return (unsigned short)((u + r) >> 16);
}
__device__ __forceinline__ float fast_tanh(float x) {
  float ex = __expf(2.f * x);
  return 1.f - __fdividef(2.f, ex + 1.f);
}
__device__ __forceinline__ void fma8(float* acc, float wt, uint4 q) {
  acc[0] += wt * bflo(q.x); acc[1] += wt * bfhi(q.x);
  acc[2] += wt * bflo(q.y); acc[3] += wt * bfhi(q.y);
  acc[4] += wt * bflo(q.z); acc[5] += wt * bfhi(q.z);
  acc[6] += wt * bflo(q.w); acc[7] += wt * bfhi(q.w);
}
__device__ __forceinline__ int tri_is64(const void* tri) {
  int z = ((const int*)tri)[2 * (threadIdx.x & 63) + 1];
  return __ballot(z == 0) == ~0ull;
}

__global__ void k_conv(const float* __restrict__ x, unsigned short* __restrict__ xb) {
  int i = blockIdx.x * blockDim.x + threadIdx.x;   // 800K quads
  if (i >= N_ENT * 16) return;
  float4 v = ((const float4*)x)[i];
  ushort4 o;
  o.x = f2bf(v.x); o.y = f2bf(v.y); o.z = f2bf(v.z); o.w = f2bf(v.w);
  ((ushort4*)xb)[i] = o;
}

// pure streaming decode: no atomics; per-wave int64 detection
__global__ void k_decode(const void* tri, unsigned short* __restrict__ srcs,
                         unsigned* __restrict__ eb) {
  int is64 = tri_is64(tri);
  int stride = gridDim.x * blockDim.x;
  if (is64) {
    const long long* t = (const long long*)tri;
    for (int e = blockIdx.x * blockDim.x + threadIdx.x; e < N_EDGE; e += stride) {
      int s = (int)t[3 * e], r = (int)t[3 * e + 1], d = (int)t[3 * e + 2];
      srcs[e] = (unsigned short)s;
      eb[e] = ((unsigned)r << 16) | (unsigned)d;
    }
  } else {
    const int* t = (const int*)tri;
    for (int e = blockIdx.x * blockDim.x + threadIdx.x; e < N_EDGE; e += stride) {
      int s = t[3 * e], r = t[3 * e + 1], d = t[3 * e + 2];
      srcs[e] = (unsigned short)s;
      eb[e] = ((unsigned)r << 16) | (unsigned)d;
    }
  }
}

// per-(chunk, node-range) histogram in LDS; no global atomics
__global__ void __launch_bounds__(256) k_hist(const unsigned short* __restrict__ srcs,
                                              unsigned short* __restrict__ hist) {
  __shared__ unsigned h[NRNG];
  int c = blockIdx.x >> 2, x = blockIdx.x & 3;
  int lo = x * NRNG;
  for (int i = threadIdx.x; i < NRNG; i += 256) h[i] = 0u;
  __syncthreads();
  int e0 = c * ECH2, e1 = e0 + ECH2;
  for (int e = e0 + threadIdx.x; e < e1; e += 256) {
    int rel = (int)srcs[e] - lo;
    if ((unsigned)rel < NRNG) atomicAdd(&h[rel], 1u);
  }
  __syncthreads();
  for (int i = threadIdx.x; i < NRNG; i += 256)
    hist[c * N_ENT + lo + i] = (unsigned short)h[i];
}

// per-node exclusive scan over chunks (hist -> cbase, tot) + block sums (bsum)
__global__ void __launch_bounds__(256) k_scanH(unsigned short* __restrict__ hist,
                                               int* __restrict__ tot, int* __restrict__ bsum) {
  int t = threadIdx.x;
  int s = blockIdx.x * CHUNK + t;
  int run = 0;
  if (t < CHUNK && s < N_ENT) {
    for (int c = 0; c < NCH; c++) {
      int v = hist[c * N_ENT + s];
      hist[c * N_ENT + s] = (unsigned short)run;
      run += v;
    }
    tot[s] = run;
  }
  int v = run;
  for (int o = 32; o; o >>= 1) v += __shfl_down(v, o);
  __shared__ int sm[4];
  if ((t & 63) == 0) sm[t >> 6] = v;
  __syncthreads();
  if (t == 0) bsum[blockIdx.x] = sm[0] + sm[1] + sm[2] + sm[3];
}

// single block: scan bsum->bbase, zero zsum, a/b/zmid precompute, W->bf16^T padded
__global__ void __launch_bounds__(256) k_scanBpre(
    const int* __restrict__ bsum, int* __restrict__ bbase, int* __restrict__ offs,
    double* zsum, const float* u, const float* enw, const float* rew, const float* rsp,
    float* av, float* bv, float* zmid,
    const float* W1, const float* W2, const float* W3, unsigned short* wt) {
  __shared__ int sm[256];
  int t = threadIdx.x;
  int v = bsum[t];
  sm[t] = v;
  __syncthreads();
  for (int d = 1; d < 256; d <<= 1) {
    int x = (t >= d) ? sm[t - d] : 0;
    __syncthreads();
    sm[t] += x;
    __syncthreads();
  }
  bbase[t] = sm[t] - v;
  if (t == 255) offs[N_ENT] = sm[255];
  if (t == 0) *zsum = 0.0;
  if (t < 64) {
    int k = t;
    float aa = 0.f, bb = 0.f;
    for (int j = 0; j < 64; j++) {
      float w = enw[j * 64 + k];
      aa += u[j] * w;
      bb += u[128 + j] * w;
    }
    av[k] = aa; bv[k] = bb;
    float z = 0.f;
    for (int c = 0; c < 64; c++) z += rew[k * 64 + c] * rsp[c];
    z *= u[64 + k];
    for (int o = 32; o; o >>= 1) z += __shfl_down(z, o);
    if (k == 0) *zmid = z;
  }
  // W[k][n] -> wt[layer][n*72+k] bf16
  for (int idx = t; idx < 4096; idx += 256) {
    int k = idx >> 6, n = idx & 63;
    wt[0 * 4608 + n * 72 + k] = f2bf(W1[idx]);
    wt[1 * 4608 + n * 72 + k] = f2bf(W2[idx]);
    wt[2 * 4608 + n * 72 + k] = f2bf(W3[idx]);
  }
}

__global__ void k_scanC(const int* __restrict__ counts, const int* __restrict__ bbase,
                        int* __restrict__ offs) {
  __shared__ int sm[256];
  int t = threadIdx.x;
  int i = blockIdx.x * CHUNK + t;
  int v = (t < CHUNK && i < N_ENT) ? counts[i] : 0;
  sm[t] = v;
  __syncthreads();
  for (int d = 1; d < 256; d <<= 1) {
    int x = (t >= d) ? sm[t - d] : 0;
    __syncthreads();
    sm[t] += x;
    __syncthreads();
  }
  if (t < CHUNK && i < N_ENT)
    offs[i] = bbase[blockIdx.x] + sm[t] - v;
}

// scatter with LDS-computed local ranks; slot = offs[s] + cbase[c][s] + lrank
__global__ void __launch_bounds__(256) k_scatter(
    const unsigned short* __restrict__ srcs, const unsigned* __restrict__ eb,
    const unsigned short* __restrict__ cbase, const int* __restrict__ offs,
    unsigned* __restrict__ epk) {
  __shared__ unsigned h[NRNG];
  int c = blockIdx.x >> 2, x = blockIdx.x & 3;
  int lo = x * NRNG;
  for (int i = threadIdx.x; i < NRNG; i += 256) h[i] = 0u;
  __syncthreads();
  int e0 = c * ECH2, e1 = e0 + ECH2;
  for (int e = e0 + threadIdx.x; e < e1; e += 256) {
    int s = (int)srcs[e];
    int rel = s - lo;
    if ((unsigned)rel < NRNG) {
      int lr = atomicAdd(&h[rel], 1u);
      epk[offs[s] + (int)cbase[c * N_ENT + s] + lr] = eb[e];
    }
  }
}

// 16 nodes per block (4 waves). Gather: wave = node, 8 lanes/edge.
// Epilogue: y = tanh(m @ W) via 2x mfma_f32_16x16x32_bf16 per wave.
template <int EPI>
__global__ void __launch_bounds__(256) k_wgc(
    const unsigned short* __restrict__ xb, const unsigned short* __restrict__ wt,
    const int* __restrict__ offs, const unsigned* __restrict__ epk,
    const float* __restrict__ re_att, unsigned short* __restrict__ yb,
    const float* __restrict__ av, const float* __restrict__ bv,
    float* __restrict__ zsrc, float* __restrict__ zdst) {
  __shared__ __align__(16) unsigned short s_m[16 * 72];   // m rows (bf16), later y
  __shared__ __align__(16) unsigned short s_wt[64 * 72];  // W^T padded
  __shared__ float s_att[N_REL];
  for (int i = threadIdx.x; i < N_REL; i += 256) s_att[i] = re_att[i];
  for (int i = threadIdx.x; i < 1152; i += 256)           // 4608 shorts as uint2
    ((uint2*)s_wt)[i] = ((const uint2*)wt)[i];
  __syncthreads();

  int wv = threadIdx.x >> 6, lane = threadIdx.x & 63;
  int g = lane >> 3, c8 = (lane & 7) * 8;
  float fa = 0.f, fb = 0.f;
  if (EPI) { fa = av[lane]; fb = bv[lane]; }

  for (int i = 0; i < 4; i++) {
    int nl = wv * 4 + i;
    int node = blockIdx.x * 16 + nl;
    int e0 = offs[node], e1 = offs[node + 1];
    float acc[8] = {0.f, 0.f, 0.f, 0.f, 0.f, 0.f, 0.f, 0.f};
    {
      uint4 q = *(const uint4*)(xb + (size_t)node * 64 + c8);
      fma8(acc, (g == 0) ? 1.f : 0.f, q);
    }
    for (int e = e0; e < e1; e += 16) {
      int ia = e + g, ib = ia + 8;
      bool va = ia < e1, vb = ib < e1;
      unsigned pa = epk[va ? ia : e0];
      unsigned pb = epk[vb ? ib : e0];
      float wa = va ? s_att[pa >> 16] : 0.f;
      float wb = vb ? s_att[pb >> 16] : 0.f;
      unsigned ra = va ? (pa & 0xffffu) : 0u;
      unsigned rb = vb ? (pb & 0xffffu) : 0u;
      uint4 qa = *(const uint4*)(xb + (size_t)ra * 64 + c8);
      uint4 qb = *(const uint4*)(xb + (size_t)rb * 64 + c8);
      fma8(acc, wa, qa);
      fma8(acc, wb, qb);
    }
#pragma unroll
    for (int off = 8; off <= 32; off <<= 1)
#pragma unroll
      for (int c = 0; c < 8; c++) acc[c] += __shfl_xor(acc[c], off);
    if (lane < 8) {   // lane j holds channels 8j..8j+7 -> m row
      uint4 pk;
      pk.x = (unsigned)f2bf(acc[0]) | ((unsigned)f2bf(acc[1]) << 16);
      pk.y = (unsigned)f2bf(acc[2]) | ((unsigned)f2bf(acc[3]) << 16);
      pk.z = (unsigned)f2bf(acc[4]) | ((unsigned)f2bf(acc[5]) << 16);
      pk.w = (unsigned)f2bf(acc[6]) | ((unsigned)f2bf(acc[7]) << 16);
      *(uint4*)&s_m[nl * 72 + lane * 8] = pk;
    }
  }
  __syncthreads();

  // wave wv computes y cols [16wv, 16wv+16): A row=lane&15, k=(lane>>4)*8+j
  int ar = (lane & 15) * 72 + (lane >> 4) * 8;
  int br = (wv * 16 + (lane & 15)) * 72 + (lane >> 4) * 8;
  s16x8 a0 = *(const s16x8*)&s_m[ar];
  s16x8 a1 = *(const s16x8*)&s_m[ar + 32];
  s16x8 b0 = *(const s16x8*)&s_wt[br];
  s16x8 b1 = *(const s16x8*)&s_wt[br + 32];
  f32x4 c = {0.f, 0.f, 0.f, 0.f};
  c = __builtin_amdgcn_mfma_f32_16x16x32_bf16(a0, b0, c, 0, 0, 0);
  c = __builtin_amdgcn_mfma_f32_16x16x32_bf16(a1, b1, c, 0, 0, 0);
  __syncthreads();   // all A-frag reads done before overwriting s_m with y
#pragma unroll
  for (int q = 0; q < 4; q++) {  // C: col=lane&15, row=(lane>>4)*4+q
    int r = (lane >> 4) * 4 + q;
    s_m[r * 72 + wv * 16 + (lane & 15)] = f2bf(fast_tanh(c[q]));
  }
  __syncthreads();

  // coalesced store: 16 rows x 128B
  {
    int r = threadIdx.x >> 4, c0 = (threadIdx.x & 15) * 4;
    ushort4 o;
    o.x = s_m[r * 72 + c0]; o.y = s_m[r * 72 + c0 + 1];
    o.z = s_m[r * 72 + c0 + 2]; o.w = s_m[r * 72 + c0 + 3];
    *(ushort4*)(yb + ((size_t)blockIdx.x * 16 + r) * 64 + c0) = o;
  }
  if (EPI) {
    for (int i = 0; i < 4; i++) {
      int nl = wv * 4 + i;
      float yf = bf2f(s_m[nl * 72 + lane]);
      float za = yf * fa, zb = yf * fb;
      for (int s = 32; s; s >>= 1) { za += __shfl_down(za, s); zb += __shfl_down(zb, s); }
      if (lane == 0) {
        int node = blockIdx.x * 16 + nl;
        zsrc[node] = za; zdst[node] = zb;
      }
    }
  }
}

// unnormalized attention aggregate + per-node partial softmax sums
__global__ void __launch_bounds__(256) k_out(
    const unsigned short* __restrict__ xb, const int* __restrict__ offs,
    const unsigned* __restrict__ epk, const float* __restrict__ zs,
    const float* __restrict__ zd, const float* zmid,
    float* __restrict__ out, float* __restrict__ snode) {
  int wid = (blockIdx.x * blockDim.x + threadIdx.x) >> 6;
  int lane = threadIdx.x & 63;
  if (wid >= N_ENT) return;
  int node = wid;
  int g = lane >> 3, c8 = (lane & 7) * 8;
  float zi = zs[node] + *zmid;
  float acc[8] = {0.f, 0.f, 0.f, 0.f, 0.f, 0.f, 0.f, 0.f};
  float s0 = 0.f;
  int e0 = offs[node], e1 = offs[node + 1];
  for (int e = e0; e < e1; e += 16) {
    int ia = e + g, ib = ia + 8;
    bool va = ia < e1, vb = ib < e1;
    unsigned pa = epk[va ? ia : e0];
    unsigned pb = epk[vb ? ib : e0];
    unsigned da = va ? (pa & 0xffffu) : 0u;
    unsigned db = vb ? (pb & 0xffffu) : 0u;
    float ca = zi + zd[da];
    float cb = zi + zd[db];
    ca = ca >= 0.f ? ca : 0.01f * ca;
    cb = cb >= 0.f ? cb : 0.01f * cb;
    float wa = va ? __expf(ca) : 0.f;
    float wb = vb ? __expf(cb) : 0.f;
    uint4 qa = *(const uint4*)(xb + (size_t)da * 64 + c8);
    uint4 qb = *(const uint4*)(xb + (size_t)db * 64 + c8);
    fma8(acc, wa, qa);
    fma8(acc, wb, qb);
    s0 += wa + wb;
  }
#pragma unroll
  for (int off = 8; off <= 32; off <<= 1) {
#pragma unroll
    for (int c = 0; c < 8; c++) acc[c] += __shfl_xor(acc[c], off);
    s0 += __shfl_xor(s0, off);
  }
  if (lane < 8) {
    float4* p = (float4*)(out + (size_t)node * 64 + lane * 8);
    p[0] = make_float4(acc[0], acc[1], acc[2], acc[3]);
    p[1] = make_float4(acc[4], acc[5], acc[6], acc[7]);
  }
  if (lane == 0) snode[node] = s0;
}

__global__ void k_red(const float* __restrict__ snode, double* zsum) {
  int stride = gridDim.x * blockDim.x;
  double s = 0.0;
  for (int i = blockIdx.x * blockDim.x + threadIdx.x; i < N_ENT; i += stride)
    s += (double)snode[i];
  for (int o = 32; o; o >>= 1) s += __shfl_down(s, o);
  __shared__ double ws_[4];
  if ((threadIdx.x & 63) == 0) ws_[threadIdx.x >> 6] = s;
  __syncthreads();
  if (threadIdx.x == 0)
    atomicAdd(zsum, ws_[0] + ws_[1] + ws_[2] + ws_[3]);
}

__global__ void k_norm(float* __restrict__ out, const double* zsum) {
  int i = blockIdx.x * blockDim.x + threadIdx.x;  // 800K quads
  if (i >= N_ENT * 16) return;
  float invZ = (float)(1.0 / *zsum);
  float4 v = ((float4*)out)[i];
  v.x *= invZ; v.y *= invZ; v.z *= invZ; v.w *= invZ;
  ((float4*)out)[i] = v;
}

extern "C" void kernel_launch(void* const* d_in, const int* in_sizes, int n_in,
                              void* d_out, int out_size, void* d_ws, size_t ws_size,
                              hipStream_t stream) {
  const float* emb   = (const float*)d_in[0];
  const float* reatt = (const float*)d_in[1];
  const float* W1    = (const float*)d_in[2];
  const float* W2    = (const float*)d_in[3];
  const float* W3    = (const float*)d_in[4];
  const float* u     = (const float*)d_in[5];
  const float* enw   = (const float*)d_in[6];
  const float* rew   = (const float*)d_in[7];
  const float* rsp   = (const float*)d_in[8];
  const void*  tri   = d_in[9];

  char* ws = (char*)d_ws;
  double*         zsum   = (double*)(ws + WS_ZSUM);
  float*          zmid   = (float*)(ws + WS_ZMID);
  float*          av     = (float*)(ws + WS_AV);
  float*          bv     = (float*)(ws + WS_BV);
  unsigned short* wt     = (unsigned short*)(ws + WS_WT);
  int*            bsum   = (int*)(ws + WS_BSUM);
  int*            bbase  = (int*)(ws + WS_BBASE);
  int*            tot    = (int*)(ws + WS_TOT);
  int*            offs   = (int*)(ws + WS_OFFS);
  float*          zsrc   = (float*)(ws + WS_ZSRC);
  float*          zdst   = (float*)(ws + WS_ZDST);
  float*          snode  = (float*)(ws + WS_SNODE);
  unsigned short* srcs   = (unsigned short*)(ws + WS_SRCS);
  unsigned*       eb     = (unsigned*)(ws + WS_EB);
  unsigned*       epk    = (unsigned*)(ws + WS_EPK);
  unsigned short* hist   = (unsigned short*)(ws + WS_HIST);
  unsigned short* xb0    = (unsigned short*)(ws + WS_XB0);
  unsigned short* xb1    = (unsigned short*)(ws + WS_XB1);  // aliases hist
  float*          out    = (float*)d_out;

  k_conv<<<3125, 256, 0, stream>>>(emb, xb0);
  k_decode<<<4096, 256, 0, stream>>>(tri, srcs, eb);
  k_hist<<<NCH * NPART, 256, 0, stream>>>(srcs, hist);
  k_scanH<<<256, 256, 0, stream>>>(hist, tot, bsum);
  k_scanBpre<<<1, 256, 0, stream>>>(bsum, bbase, offs, zsum, u, enw, rew, rsp,
                                    av, bv, zmid, W1, W2, W3, wt);
  k_scanC<<<256, 256, 0, stream>>>(tot, bbase, offs);
  k_scatter<<<NCH * NPART, 256, 0, stream>>>(srcs, eb, hist, offs, epk);

  k_wgc<0><<<3125, 256, 0, stream>>>(xb0, wt + 0 * 4608, offs, epk, reatt, xb1,
                                     nullptr, nullptr, nullptr, nullptr);
  k_wgc<0><<<3125, 256, 0, stream>>>(xb1, wt + 1 * 4608, offs, epk, reatt, xb0,
                                     nullptr, nullptr, nullptr, nullptr);
  k_wgc<1><<<3125, 256, 0, stream>>>(xb0, wt + 2 * 4608, offs, epk, reatt, xb1,
                                     av, bv, zsrc, zdst);

  k_out<<<12500, 256, 0, stream>>>(xb1, offs, epk, zsrc, zdst, zmid, out, snode);
  k_red<<<196, 256, 0, stream>>>(snode, zsum);
  k_norm<<<3125, 256, 0, stream>>>(out, zsum);
}